// Round 12
// baseline (98.235 us; speedup 1.0000x reference)
//
#include <hip/hip_runtime.h>
#include <math.h>

#define NA 16
#define NS 32
#define NB 100
#define NE 12
#define DD 512
#define NQ (NA*NS)          // 512
#define NC (NA*NE)          // 192
#define OUT_SIM_OFF (NQ*NC) // 98304
#define EPSF 1e-5f
#define DELTAF 0.2f
#define EPS_R 0.15f

// ws layout (floats): [0]=vis_sum, [1]=vis_cnt, [2..8194)=Sf, [12288..]=B fp16 frags
#define WS_B_FOFF 12288
// B frag region: [kc2=8][nt=12][ks=2][512] shorts = 98304 shorts = 192 KB (L2/L3-resident)

typedef _Float16 f16x8 __attribute__((ext_vector_type(8)));
typedef float f32x4 __attribute__((ext_vector_type(4)));

// ---------------- K0: pre-convert word -> fragment-major fp16 in ws -------------
// grid 192 = kcc*12 + nt (kcc = 32-wide K chunk). lane l, elem j =
// word[nt*16+(l&15)][kcc*32+(l>>4)*8+j] -> frag [kcc>>1][nt][kcc&1]
__global__ __launch_bounds__(64) void k0_conv(
    const float* __restrict__ word, float* __restrict__ ws)
{
    const int kcc = blockIdx.x / 12;
    const int nt  = blockIdx.x - kcc*12;
    const int l   = threadIdx.x;
    if (blockIdx.x == 0 && l < 2) ws[l] = 0.f;   // zero vis_sum/vis_cnt each launch

    const int col = nt*16 + (l & 15);
    const int k   = kcc*32 + (l >> 4)*8;
    const float* src = word + (size_t)col*DD + k;
    float4 v0 = *(const float4*)(src);
    float4 v1 = *(const float4*)(src + 4);
    f16x8 hv;
    hv[0]=(_Float16)v0.x; hv[1]=(_Float16)v0.y; hv[2]=(_Float16)v0.z; hv[3]=(_Float16)v0.w;
    hv[4]=(_Float16)v1.x; hv[5]=(_Float16)v1.y; hv[6]=(_Float16)v1.z; hv[7]=(_Float16)v1.w;
    unsigned short* wsB = (unsigned short*)(ws + WS_B_FOFF);
    const int kc2 = kcc >> 1, ks = kcc & 1;
    *(f16x8*)&wsB[(size_t)(((kc2*12 + nt)*2 + ks)*512) + l*8] = hv;
}

// ---------------- K1: barrier-free fp16 MFMA GEMM -------------------------------
// grid 512 (one q-group), 512 threads = 8 waves. Wave w owns rows 16w..16w+15
// (rows>=100 clamped+masked) x ALL 192 cols -> acc[12] f32x4.
// A: lane-local direct global->VGPR (lane l elem j = vis[16w+(l&15)][kb+(l>>4)*8+j]),
//    prefetched one 64-wide chunk ahead. 100% L2-line utilization.
// B: fragments read DIRECTLY from pre-converted wsB (L2/L3-resident) — no LDS,
//    no __syncthreads anywhere in the K loop; waves run free, TLP feeds HBM.
__global__ __launch_bounds__(512, 2) void k1_mfma(
    const float* __restrict__ vis, const float* __restrict__ word,
    const unsigned short* __restrict__ wsB,
    const int* __restrict__ ent, float* __restrict__ out)
{
    __shared__ __align__(16) char pool[16640];   // epilogue scratch only
    float* part_v = (float*)pool;                  // [8][192] = 6144 B
    int*   part_i = (int*)(pool + 6144);           // [8][192] = 6144 B
    float* colmax = (float*)(pool + 12288);        // [192]
    int*   cnts   = (int*)(pool + 13056);          // [192]
    int*   cand   = (int*)(pool + 13824);          // [192]
    int*   flist  = (int*)(pool + 14592);          // [192]
    int*   nflag  = (int*)(pool + 15360);

    const int t    = threadIdx.x;
    const int lane = t & 63;
    const int w    = t >> 6;     // wave id = row-stripe id
    const int q    = blockIdx.x;
    const float* visq = vis + (size_t)q * NB * DD;

    f32x4 acc[12];
    #pragma unroll
    for (int nt = 0; nt < 12; nt++) acc[nt] = (f32x4)0.f;

    // A source pointer for this lane (row clamped; garbage rows masked in epilogue)
    int arow = w*16 + (lane & 15);
    const float* aptr = visq + (size_t)(arow < NB ? arow : 0)*DD + ((lane >> 4) << 3);

    float4 ar[2][4];   // [chunk parity][4 float4] — static indices after full unroll

    // ---- prologue: A chunk 0 loads
    {
        const float* p_ = aptr;
        ar[0][0] = *(const float4*)(p_);
        ar[0][1] = *(const float4*)(p_ + 4);
        ar[0][2] = *(const float4*)(p_ + 32);
        ar[0][3] = *(const float4*)(p_ + 36);
    }

    #pragma unroll
    for (int kc = 0; kc < 8; ++kc) {
        const int p = kc & 1;
        if (kc < 7) {   // prefetch next A chunk (in flight during this chunk's MFMAs)
            const float* p_ = aptr + (kc+1)*64;
            ar[p^1][0] = *(const float4*)(p_);
            ar[p^1][1] = *(const float4*)(p_ + 4);
            ar[p^1][2] = *(const float4*)(p_ + 32);
            ar[p^1][3] = *(const float4*)(p_ + 36);
        }
        // convert this chunk's A regs -> 2 fragments (ks=0,1)
        f16x8 af0, af1;
        af0[0]=(_Float16)ar[p][0].x; af0[1]=(_Float16)ar[p][0].y;
        af0[2]=(_Float16)ar[p][0].z; af0[3]=(_Float16)ar[p][0].w;
        af0[4]=(_Float16)ar[p][1].x; af0[5]=(_Float16)ar[p][1].y;
        af0[6]=(_Float16)ar[p][1].z; af0[7]=(_Float16)ar[p][1].w;
        af1[0]=(_Float16)ar[p][2].x; af1[1]=(_Float16)ar[p][2].y;
        af1[2]=(_Float16)ar[p][2].z; af1[3]=(_Float16)ar[p][2].w;
        af1[4]=(_Float16)ar[p][3].x; af1[5]=(_Float16)ar[p][3].y;
        af1[6]=(_Float16)ar[p][3].z; af1[7]=(_Float16)ar[p][3].w;
        // MFMA: 12 nt x 2 ks, B fragments straight from L2-resident wsB
        const unsigned short* bbase = wsB + (size_t)kc*12288 + lane*8;
        #pragma unroll
        for (int nt = 0; nt < 12; nt++) {
            f16x8 bf0 = *((const f16x8*)(bbase + (nt*2+0)*512));
            f16x8 bf1 = *((const f16x8*)(bbase + (nt*2+1)*512));
            acc[nt] = __builtin_amdgcn_mfma_f32_16x16x32_f16(af0, bf0, acc[nt], 0, 0, 0);
            acc[nt] = __builtin_amdgcn_mfma_f32_16x16x32_f16(af1, bf1, acc[nt], 0, 0, 0);
        }
    }

    // ---- E1: per-wave per-column max/argmax over the wave's 16 rows ----
    // C frag: col = nt*16 + (lane&15), row = 16w + (lane>>4)*4 + r
    #pragma unroll
    for (int nt = 0; nt < 12; nt++) {
        float bv = -INFINITY; int bg = 1000;
        #pragma unroll
        for (int r = 0; r < 4; r++) {
            int g = w*16 + ((lane>>4)<<2) + r;
            float v = acc[nt][r];
            if (g < NB && (v > bv || (v == bv && g < bg))) { bv = v; bg = g; }
        }
        #pragma unroll
        for (int off = 16; off <= 32; off <<= 1) {
            float ov = __shfl_xor(bv, off);
            int   og = __shfl_xor(bg, off);
            if (ov > bv || (ov == bv && og < bg)) { bv = ov; bg = og; }
        }
        if (lane < 16) {
            part_v[w*NC + nt*16 + lane] = bv;
            part_i[w*NC + nt*16 + lane] = bg;
        }
    }
    if (t < NC) { cnts[t] = 0; cand[t] = 0; }
    if (t == 0) *nflag = 0;
    __syncthreads();

    // ---- E2: reduce across 8 waves (row-ascending => first-occurrence ties) ----
    float fbv = 0.f; int fbg = 0; bool fmask = true;
    if (t < NC) {
        fbv = -INFINITY; fbg = 1000;
        #pragma unroll
        for (int ww = 0; ww < 8; ww++) {
            float v = part_v[ww*NC + t]; int g = part_i[ww*NC + t];
            if (v > fbv || (v == fbv && g < fbg)) { fbv = v; fbg = g; }
        }
        int a2 = t / NE, e = t - a2*NE;
        fmask = (e >= ent[a2]);
        colmax[t] = fmask ? INFINITY : fbv;
    }
    __syncthreads();

    // ---- E3: collect candidate rows within EPS_R of column max ----
    #pragma unroll
    for (int nt = 0; nt < 12; nt++) {
        int col = nt*16 + (lane & 15);
        float cm = colmax[col] - EPS_R;
        #pragma unroll
        for (int r = 0; r < 4; r++) {
            int g = w*16 + ((lane>>4)<<2) + r;
            float v = acc[nt][r];
            if (g < NB && v >= cm) {
                int s = atomicAdd(&cnts[col], 1);
                if (s < 3) atomicOr(&cand[col], (g + 1) << (8*s));
            }
        }
    }
    __syncthreads();

    // ---- E4: write non-flagged columns; build flagged list ----
    if (t < NC) {
        if (fmask) {
            out[(size_t)q*NC + t] = 0.f;
            out[OUT_SIM_OFF + (size_t)q*NC + t] = 0.f;
        } else if (cnts[t] <= 1) {
            out[(size_t)q*NC + t] = (float)fbg;
            out[OUT_SIM_OFF + (size_t)q*NC + t] = fbv;
        } else {
            int idx = atomicAdd(nflag, 1);
            flist[idx] = t;
        }
    }
    __syncthreads();

    // ---- E5: exact fp32 rescue of flagged columns ----
    const int nf = *nflag;
    for (int f = w; f < nf; f += 8) {
        int col = flist[f];
        int cnt = cnts[col];
        const float* wc = word + (size_t)col*DD;
        float bv; int bg;
        if (cnt <= 3) {
            int grp = lane >> 4, li = lane & 15;
            int cpk = cand[col];
            int myrow = (grp < cnt) ? (((cpk >> (8*grp)) & 255) - 1) : -1;
            float d = 0.f;
            if (myrow >= 0) {
                const float* vr = visq + (size_t)myrow*DD + li*32;
                const float* wb = wc + li*32;
                #pragma unroll
                for (int m = 0; m < 8; ++m) {
                    float4 a = *(const float4*)(vr + m*4);
                    float4 b = *(const float4*)(wb + m*4);
                    d = fmaf(a.x, b.x, d); d = fmaf(a.y, b.y, d);
                    d = fmaf(a.z, b.z, d); d = fmaf(a.w, b.w, d);
                }
            }
            #pragma unroll
            for (int off = 1; off <= 8; off <<= 1) d += __shfl_xor(d, off);
            float v0 = __shfl(d, 0), v1 = __shfl(d, 16), v2 = __shfl(d, 32);
            int r0 = ( cpk        & 255) - 1;
            int r1 = ((cpk >> 8)  & 255) - 1;
            int r2 = ((cpk >> 16) & 255) - 1;
            bv = v0; bg = r0;
            if (cnt >= 2 && (v1 > bv || (v1 == bv && r1 < bg))) { bv = v1; bg = r1; }
            if (cnt >= 3 && (v2 > bv || (v2 == bv && r2 < bg))) { bv = v2; bg = r2; }
        } else {
            float mbv = -INFINITY; int mbg = 1000;
            for (int r = lane; r < NB; r += 64) {
                float d = 0.f;
                const float* vr = visq + (size_t)r*DD;
                for (int m = 0; m < DD/4; ++m) {
                    float4 a = *(const float4*)(vr + m*4);
                    float4 b = *(const float4*)(wc + m*4);
                    d = fmaf(a.x, b.x, d); d = fmaf(a.y, b.y, d);
                    d = fmaf(a.z, b.z, d); d = fmaf(a.w, b.w, d);
                }
                if (d > mbv || (d == mbv && r < mbg)) { mbv = d; mbg = r; }
            }
            bv = mbv; bg = mbg;
            #pragma unroll
            for (int off = 32; off >= 1; off >>= 1) {
                float ov = __shfl_xor(bv, off); int og = __shfl_xor(bg, off);
                if (ov > bv || (ov == bv && og < bg)) { bv = ov; bg = og; }
            }
        }
        if (lane == 0) {
            out[(size_t)q*NC + col] = (float)bg;
            out[OUT_SIM_OFF + (size_t)q*NC + col] = bv;
        }
    }
}

// ---------------- K23: fused vis path (blocks 0..191) + margin path (192..207) ---
__global__ __launch_bounds__(256) void k23_fused(
    const float* __restrict__ vis, const int* __restrict__ ent,
    const float* __restrict__ out_ro, float* __restrict__ ws)
{
    __shared__ __align__(16) char pool[74240];
    const int t = threadIdx.x;

    if (blockIdx.x < 192) {
        // ================= K2 body: per (a,e) vis-loss partials ==================
        const int a = blockIdx.x / NE;
        const int e = blockIdx.x - a*NE;
        if (e >= ent[a]) return;

        float* VT   = (float*)pool;            // [512][36]
        float* simv = (float*)(pool + 73728);  // [32]
        int*   indv = (int*)(pool + 73856);    // [32]
        float* scl  = (float*)(pool + 73984);  // [32]
        float* wsum = (float*)(pool + 74112);  // [4]
        float* wcnt = (float*)(pool + 74128);  // [4]

        if (t < NS) {
            int q = a*NS + t;
            simv[t] = out_ro[OUT_SIM_OFF + (size_t)q*NC + a*NE + e];
            indv[t] = (int)out_ro[(size_t)q*NC + a*NE + e];
        }
        __syncthreads();
        if (t < NS) {
            float v = simv[t];
            float mn = v, mx = v;
            #pragma unroll
            for (int off = 16; off >= 1; off >>= 1) {
                mn = fminf(mn, __shfl_xor(mn, off));
                mx = fmaxf(mx, __shfl_xor(mx, off));
            }
            simv[t] = (v - mn) / (mx - mn + EPSF);
        }
        __syncthreads();

        const int g = t >> 3, j = t & 7;
        const float* src = vis + (size_t)indv[g]*DD;
        float ss = 0.f;
        #pragma unroll
        for (int i = 0; i < 16; i++) {
            int k4 = j + 8*i;
            float4 v = *(const float4*)(src + k4*4);
            ss = fmaf(v.x,v.x, fmaf(v.y,v.y, fmaf(v.z,v.z, fmaf(v.w,v.w, ss))));
            int k = k4*4;
            VT[(k+0)*36 + g] = v.x;
            VT[(k+1)*36 + g] = v.y;
            VT[(k+2)*36 + g] = v.z;
            VT[(k+3)*36 + g] = v.w;
        }
        #pragma unroll
        for (int off = 4; off >= 1; off >>= 1) ss += __shfl_xor(ss, off);
        if (j == 0) scl[g] = simv[g] / (sqrtf(ss) + EPSF);
        __syncthreads();

        const int s = t >> 3, tq = t & 7;
        float g0=0.f, g1=0.f, g2=0.f, g3=0.f;
        for (int k = 0; k < DD; k++) {
            float vs = VT[k*36 + s];
            float4 vt = *(const float4*)&VT[k*36 + tq*4];
            g0 = fmaf(vs, vt.x, g0);
            g1 = fmaf(vs, vt.y, g1);
            g2 = fmaf(vs, vt.z, g2);
            g3 = fmaf(vs, vt.w, g3);
        }
        float lsum = 0.f, lcnt = 0.f;
        float sc_s = scl[s];
        float gv[4] = {g0, g1, g2, g3};
        #pragma unroll
        for (int jj = 0; jj < 4; jj++) {
            int tt = tq*4 + jj;
            if (tt != s) {
                float val = 1.f - sc_s * scl[tt] * gv[jj];
                lsum += val;
                if (val != 0.f) lcnt += 1.f;
            }
        }
        #pragma unroll
        for (int off = 32; off >= 1; off >>= 1) {
            lsum += __shfl_xor(lsum, off);
            lcnt += __shfl_xor(lcnt, off);
        }
        const int wid = t >> 6, lane = t & 63;
        if (lane == 0) { wsum[wid] = lsum; wcnt[wid] = lcnt; }
        __syncthreads();
        if (t == 0) {
            atomicAdd(&ws[0], wsum[0]+wsum[1]+wsum[2]+wsum[3]);
            atomicAdd(&ws[1], wcnt[0]+wcnt[1]+wcnt[2]+wcnt[3]);
        }
    } else {
        // ================= K3 body: per a margin Sf ==============================
        const int a = blockIdx.x - 192;
        float* Ss  = (float*)pool;             // [32][192]
        float* Smn = (float*)(pool + 24576);   // [192]
        float* Smx = (float*)(pool + 25344);   // [192]

        for (int e2 = t; e2 < NS*NC; e2 += 256) {
            int s = e2 / NC, c = e2 - (e2/NC)*NC;
            Ss[s*NC + c] = out_ro[OUT_SIM_OFF + (size_t)(a*NS + s)*NC + c];
        }
        __syncthreads();
        if (t < NC) {
            float mn = INFINITY, mx = -INFINITY;
            #pragma unroll
            for (int s = 0; s < NS; s++) {
                float v = Ss[s*NC + t];
                mn = fminf(mn, v); mx = fmaxf(mx, v);
            }
            Smn[t] = mn; Smx[t] = mx;
        }
        __syncthreads();
        for (int p = t; p < NS*NA; p += 256) {
            int s = p >> 4, b = p & 15;
            int eb = ent[b];
            float dv = (eb == 0) ? 1.f : (float)eb;
            float sum = 0.f;
            #pragma unroll
            for (int e2 = 0; e2 < NE; e2++) {
                int c = b*NE + e2;
                float S = Ss[s*NC + c];
                float r = (S - Smn[c]) / (Smx[c] - Smn[c] + EPSF);
                sum += S * r;
            }
            ws[2 + a*(NS*NA) + s*NA + b] = sum / dv;
        }
    }
}

// ---------------- K4: final combine ----------------------------------------------
__global__ __launch_bounds__(256) void k4_final(
    const float* __restrict__ ws_ro, float* __restrict__ out)
{
    __shared__ float Sf[NA][NS][NA];
    __shared__ float dg[NA][NS];
    __shared__ float wred[4];
    const int t = threadIdx.x;
    for (int e2 = t; e2 < NA*NS*NA; e2 += 256)
        ((float*)Sf)[e2] = ws_ro[2 + e2];
    __syncthreads();
    for (int p = t; p < NA*NS; p += 256) {
        int aa = p >> 5, s = p & 31;
        dg[aa][s] = Sf[aa][s][aa];
    }
    __syncthreads();
    float fsum = 0.f;
    for (int p = t; p < NA*NS; p += 256) {
        int i = p >> 5, s = p & 31;
        float d = dg[i][s];
        float t1 = 0.f, t2 = 0.f;
        #pragma unroll
        for (int x = 0; x < NA; x++) {
            t1 += fmaxf(Sf[x][s][i] - d + DELTAF, 0.f);
            t2 += fmaxf(Sf[i][s][x] - d + DELTAF, 0.f);
        }
        fsum += (t1 + t2) * (1.f/16.f);
    }
    #pragma unroll
    for (int off = 32; off >= 1; off >>= 1) fsum += __shfl_xor(fsum, off);
    const int wid = t >> 6, lane = t & 63;
    if (lane == 0) wred[wid] = fsum;
    __syncthreads();
    if (t == 0) {
        float frame_mean = (wred[0]+wred[1]+wred[2]+wred[3]) / 512.f;
        float vis_loss = ws_ro[0] / ws_ro[1];
        out[2*OUT_SIM_OFF] = (frame_mean + 1.0f * vis_loss) * 10.f;
    }
}

extern "C" void kernel_launch(void* const* d_in, const int* in_sizes, int n_in,
                              void* d_out, int out_size, void* d_ws, size_t ws_size,
                              hipStream_t stream)
{
    (void)in_sizes; (void)n_in; (void)out_size; (void)ws_size;
    const float* vis  = (const float*)d_in[0];
    const float* word = (const float*)d_in[1];
    const int*   ent  = (const int*)d_in[2];
    float* out = (float*)d_out;
    float* ws  = (float*)d_ws;
    const unsigned short* wsB = (const unsigned short*)(ws + WS_B_FOFF);

    k0_conv<<<192, 64, 0, stream>>>(word, ws);
    k1_mfma<<<NQ, 512, 0, stream>>>(vis, word, wsB, ent, out);
    k23_fused<<<208, 256, 0, stream>>>(vis, ent, out, ws);
    k4_final<<<1, 256, 0, stream>>>(ws, out);
}

// Round 13
// 56.821 us; speedup vs baseline: 1.7289x; 1.7289x over previous
//
#include <hip/hip_runtime.h>
#include <math.h>

#define NA 16
#define NS 32
#define NB 100
#define NE 12
#define DD 512
#define NQ (NA*NS)          // 512
#define NC (NA*NE)          // 192
#define OUT_SIM_OFF (NQ*NC) // 98304
#define EPSF 1e-5f
#define DELTAF 0.2f
#define EPS_R 0.15f

// ws layout (floats): [0]=vis_sum, [1]=vis_cnt, [2..8194)=Sf, [12288..]=B fp16 frags
#define WS_B_FOFF 12288
// B frag region: [kc2=8][nt=12][ks=2][512] shorts = 98304 shorts = 192 KB

typedef _Float16 f16x8 __attribute__((ext_vector_type(8)));
typedef float f32x4 __attribute__((ext_vector_type(4)));

// ---------------- K0: pre-convert word -> fragment-major fp16 in ws -------------
// grid 192 = kcc*12 + nt (kcc = 32-wide K chunk). lane l, elem j =
// word[nt*16+(l&15)][kcc*32+(l>>4)*8+j] -> frag [kcc>>1][nt][kcc&1]
__global__ __launch_bounds__(64) void k0_conv(
    const float* __restrict__ word, float* __restrict__ ws)
{
    const int kcc = blockIdx.x / 12;
    const int nt  = blockIdx.x - kcc*12;
    const int l   = threadIdx.x;
    if (blockIdx.x == 0 && l < 2) ws[l] = 0.f;   // zero vis_sum/vis_cnt each launch

    const int col = nt*16 + (l & 15);
    const int k   = kcc*32 + (l >> 4)*8;
    const float* src = word + (size_t)col*DD + k;
    float4 v0 = *(const float4*)(src);
    float4 v1 = *(const float4*)(src + 4);
    f16x8 hv;
    hv[0]=(_Float16)v0.x; hv[1]=(_Float16)v0.y; hv[2]=(_Float16)v0.z; hv[3]=(_Float16)v0.w;
    hv[4]=(_Float16)v1.x; hv[5]=(_Float16)v1.y; hv[6]=(_Float16)v1.z; hv[7]=(_Float16)v1.w;
    unsigned short* wsB = (unsigned short*)(ws + WS_B_FOFF);
    const int kc2 = kcc >> 1, ks = kcc & 1;
    *(f16x8*)&wsB[(size_t)(((kc2*12 + nt)*2 + ks)*512) + l*8] = hv;
}

// ---------------- K1: fp16 MFMA GEMM (KT=64) + max/argmax + fused exact rescue --
// grid 512 (one q-group), 512 threads = 8 waves; wave (wm = wid>>2, wn = wid&3).
// Tile M=128 x N=192, K chunks of 64 (8 chunks, 8 barrier drains).
// LDS 80KB: A 2x16KB (reg-staged fp16, lane-linear 16B writes),
//           B 2x24KB (global_load_lds DMA from pre-converted ws).
__global__ __launch_bounds__(512, 4) void k1_mfma(
    const float* __restrict__ vis, const float* __restrict__ word,
    const unsigned short* __restrict__ wsB,
    const int* __restrict__ ent, float* __restrict__ out)
{
    __shared__ __align__(16) char pool[81920];
    unsigned short* Abuf = (unsigned short*)pool;            // [2][8mt*2ks][512] = 2 x 8192 shorts
    unsigned short* Bbuf = (unsigned short*)(pool + 32768);  // [2][12nt*2ks][512] = 2 x 12288 shorts
    // epilogue aliases (pool[0..8KB) = Abuf buf0; last chunk (kc=7) reads buf1 -> disjoint)
    float* part_v = (float*)pool;                 // [2][192]
    int*   part_i = (int*)(pool + 1536);          // [2][192]
    float* colmax = (float*)(pool + 3072);        // [192]
    int*   cnts   = (int*)(pool + 3840);          // [192]
    int*   cand   = (int*)(pool + 4608);          // [192]
    int*   flist  = (int*)(pool + 5376);          // [192]
    int*   nflag  = (int*)(pool + 6144);

    const int t    = threadIdx.x;
    const int lane = t & 63;
    const int wid  = t >> 6;
    const int wm   = wid >> 2;   // 0..1
    const int wn   = wid & 3;    // 0..3
    const int q    = blockIdx.x;
    const float* visq = vis + (size_t)q * NB * DD;

    f32x4 acc[4][3];
    #pragma unroll
    for (int mi = 0; mi < 4; mi++)
        #pragma unroll
        for (int ni = 0; ni < 3; ni++) acc[mi][ni] = (f32x4)0.f;

    float4 ar[4];   // A prefetch: thread owns (mt = t>>6, l = t&63), both ks

    #define A_LOAD(kb)                                                         \
        {   int l_ = t & 63;                                                   \
            int row = ((t >> 6) << 4) + (l_ & 15);                             \
            ar[0] = make_float4(0.f,0.f,0.f,0.f); ar[1] = ar[0];               \
            ar[2] = ar[0]; ar[3] = ar[0];                                      \
            if (row < NB) {                                                    \
                const float* p_ = visq + (size_t)row*DD + (kb) + ((l_>>4)<<3); \
                ar[0] = *(const float4*)p_;                                    \
                ar[1] = *(const float4*)(p_ + 4);                              \
                ar[2] = *(const float4*)(p_ + 32);                             \
                ar[3] = *(const float4*)(p_ + 36); } }
    #define A_STORE(pn)                                                       \
        {   int mt_ = t >> 6;                                                 \
            f16x8 h0, h1;                                                     \
            h0[0]=(_Float16)ar[0].x; h0[1]=(_Float16)ar[0].y;                 \
            h0[2]=(_Float16)ar[0].z; h0[3]=(_Float16)ar[0].w;                 \
            h0[4]=(_Float16)ar[1].x; h0[5]=(_Float16)ar[1].y;                 \
            h0[6]=(_Float16)ar[1].z; h0[7]=(_Float16)ar[1].w;                 \
            h1[0]=(_Float16)ar[2].x; h1[1]=(_Float16)ar[2].y;                 \
            h1[2]=(_Float16)ar[2].z; h1[3]=(_Float16)ar[2].w;                 \
            h1[4]=(_Float16)ar[3].x; h1[5]=(_Float16)ar[3].y;                 \
            h1[6]=(_Float16)ar[3].z; h1[7]=(_Float16)ar[3].w;                 \
            *(f16x8*)&Abuf[(pn)*8192 + (mt_*2+0)*512 + (t&63)*8] = h0;        \
            *(f16x8*)&Abuf[(pn)*8192 + (mt_*2+1)*512 + (t&63)*8] = h1; }
    // B staging: 1536 x 16B transfers per chunk; 3 per thread
    #define B_STAGE(kcn, pn)                                                   \
        {   const unsigned short* bsrc = wsB + (size_t)(kcn)*12288;            \
            unsigned short* bdst = Bbuf + (pn)*12288;                          \
            _Pragma("unroll")                                                  \
            for (int i = 0; i < 3; i++)                                        \
                __builtin_amdgcn_global_load_lds(                              \
                    (const void*)(bsrc + ((size_t)(i*512 + wid*64 + lane))*8), \
                    (void*)(bdst + (i*512 + wid*64)*8), 16, 0, 0); }

    // ---- prologue: stage chunk 0 into buf 0
    {
        B_STAGE(0, 0);
        A_LOAD(0);
        A_STORE(0);
    }
    __syncthreads();

    for (int kc = 0; kc < 8; ++kc) {
        const int p = kc & 1;
        if (kc < 7) {
            A_LOAD((kc+1)*64);   // issue early (T14); in flight during MFMAs
            B_STAGE(kc+1, p^1);
        }
        // ---- MFMA phase on buffer p: 2 k-substeps x 12 MFMA
        {
            const unsigned short* Bp = Bbuf + p*12288;
            const unsigned short* Ap = Abuf + p*8192;
            #pragma unroll
            for (int ks = 0; ks < 2; ks++) {
                f16x8 bf[3];
                #pragma unroll
                for (int ni = 0; ni < 3; ni++)
                    bf[ni] = *((const f16x8*)&Bp[((wn*3 + ni)*2 + ks)*512 + lane*8]);
                #pragma unroll
                for (int mi = 0; mi < 4; mi++) {
                    f16x8 af = *((const f16x8*)&Ap[((wm*4 + mi)*2 + ks)*512 + lane*8]);
                    #pragma unroll
                    for (int ni = 0; ni < 3; ni++)
                        acc[mi][ni] = __builtin_amdgcn_mfma_f32_16x16x32_f16(af, bf[ni], acc[mi][ni], 0, 0, 0);
                }
            }
        }
        if (kc < 7) { A_STORE(p^1); }   // convert late
        __syncthreads();                // drains vmcnt (incl. DMA) + lgkm
    }

    // ---- E1: per-wave partial max/argmax; init flag structures ----
    // C frag: col = lane&15, row = (lane>>4)*4 + r
    #pragma unroll
    for (int ni = 0; ni < 3; ni++) {
        float bv = -INFINITY; int bg = 1000;
        #pragma unroll
        for (int mi = 0; mi < 4; mi++)
            #pragma unroll
            for (int r = 0; r < 4; r++) {
                int g = wm*64 + mi*16 + ((lane>>4)<<2) + r;
                float v = acc[mi][ni][r];
                if (g < NB && (v > bv || (v == bv && g < bg))) { bv = v; bg = g; }
            }
        #pragma unroll
        for (int off = 16; off <= 32; off <<= 1) {
            float ov = __shfl_xor(bv, off);
            int   og = __shfl_xor(bg, off);
            if (ov > bv || (ov == bv && og < bg)) { bv = ov; bg = og; }
        }
        if (lane < 16) {
            int col = wn*48 + ni*16 + lane;
            part_v[wm*NC + col] = bv; part_i[wm*NC + col] = bg;
        }
    }
    if (t < NC) { cnts[t] = 0; cand[t] = 0; }
    if (t == 0) *nflag = 0;
    __syncthreads();

    // ---- E2: final per-column reduce + colmax ----
    float fbv = 0.f; int fbg = 0; bool fmask = true;
    if (t < NC) {
        fbv = part_v[t]; fbg = part_i[t];
        float v1 = part_v[NC + t]; int g1 = part_i[NC + t];
        if (v1 > fbv || (v1 == fbv && g1 < fbg)) { fbv = v1; fbg = g1; }
        int a2 = t / NE, e = t - a2*NE;
        fmask = (e >= ent[a2]);
        colmax[t] = fmask ? INFINITY : fbv;
    }
    __syncthreads();

    // ---- E3: collect candidate rows within EPS_R of column max ----
    #pragma unroll
    for (int ni = 0; ni < 3; ni++) {
        int col = wn*48 + ni*16 + (lane & 15);
        float cm = colmax[col] - EPS_R;
        #pragma unroll
        for (int mi = 0; mi < 4; mi++)
            #pragma unroll
            for (int r = 0; r < 4; r++) {
                int g = wm*64 + mi*16 + ((lane>>4)<<2) + r;
                float v = acc[mi][ni][r];
                if (g < NB && v >= cm) {
                    int s = atomicAdd(&cnts[col], 1);
                    if (s < 3) atomicOr(&cand[col], (g + 1) << (8*s));
                }
            }
    }
    __syncthreads();

    // ---- E4: write non-flagged columns; build flagged list ----
    if (t < NC) {
        if (fmask) {
            out[(size_t)q*NC + t] = 0.f;
            out[OUT_SIM_OFF + (size_t)q*NC + t] = 0.f;
        } else if (cnts[t] <= 1) {
            out[(size_t)q*NC + t] = (float)fbg;
            out[OUT_SIM_OFF + (size_t)q*NC + t] = fbv;
        } else {
            int idx = atomicAdd(nflag, 1);
            flist[idx] = t;
        }
    }
    __syncthreads();

    // ---- E5: exact fp32 rescue of flagged columns ----
    const int nf = *nflag;
    for (int f = wid; f < nf; f += 8) {
        int col = flist[f];
        int cnt = cnts[col];
        const float* wc = word + (size_t)col*DD;
        float bv; int bg;
        if (cnt <= 3) {
            // 16 lanes per candidate row, 32 floats each
            int grp = lane >> 4, li = lane & 15;
            int cpk = cand[col];
            int myrow = (grp < cnt) ? (((cpk >> (8*grp)) & 255) - 1) : -1;
            float d = 0.f;
            if (myrow >= 0) {
                const float* vr = visq + (size_t)myrow*DD + li*32;
                const float* wb = wc + li*32;
                #pragma unroll
                for (int m = 0; m < 8; ++m) {
                    float4 a = *(const float4*)(vr + m*4);
                    float4 b = *(const float4*)(wb + m*4);
                    d = fmaf(a.x, b.x, d); d = fmaf(a.y, b.y, d);
                    d = fmaf(a.z, b.z, d); d = fmaf(a.w, b.w, d);
                }
            }
            #pragma unroll
            for (int off = 1; off <= 8; off <<= 1) d += __shfl_xor(d, off);
            float v0 = __shfl(d, 0), v1 = __shfl(d, 16), v2 = __shfl(d, 32);
            int r0 = ( cpk        & 255) - 1;
            int r1 = ((cpk >> 8)  & 255) - 1;
            int r2 = ((cpk >> 16) & 255) - 1;
            bv = v0; bg = r0;
            if (cnt >= 2 && (v1 > bv || (v1 == bv && r1 < bg))) { bv = v1; bg = r1; }
            if (cnt >= 3 && (v2 > bv || (v2 == bv && r2 < bg))) { bv = v2; bg = r2; }
        } else {
            float mbv = -INFINITY; int mbg = 1000;
            for (int r = lane; r < NB; r += 64) {
                float d = 0.f;
                const float* vr = visq + (size_t)r*DD;
                for (int m = 0; m < DD/4; ++m) {
                    float4 a = *(const float4*)(vr + m*4);
                    float4 b = *(const float4*)(wc + m*4);
                    d = fmaf(a.x, b.x, d); d = fmaf(a.y, b.y, d);
                    d = fmaf(a.z, b.z, d); d = fmaf(a.w, b.w, d);
                }
                if (d > mbv || (d == mbv && r < mbg)) { mbv = d; mbg = r; }
            }
            bv = mbv; bg = mbg;
            #pragma unroll
            for (int off = 32; off >= 1; off >>= 1) {
                float ov = __shfl_xor(bv, off); int og = __shfl_xor(bg, off);
                if (ov > bv || (ov == bv && og < bg)) { bv = ov; bg = og; }
            }
        }
        if (lane == 0) {
            out[(size_t)q*NC + col] = (float)bg;
            out[OUT_SIM_OFF + (size_t)q*NC + col] = bv;
        }
    }
}

// ---------------- K23: fused vis path (blocks 0..191) + margin path (192..207) ---
__global__ __launch_bounds__(256) void k23_fused(
    const float* __restrict__ vis, const int* __restrict__ ent,
    const float* __restrict__ out_ro, float* __restrict__ ws)
{
    __shared__ __align__(16) char pool[74240];
    const int t = threadIdx.x;

    if (blockIdx.x < 192) {
        // ================= K2 body: per (a,e) vis-loss partials ==================
        const int a = blockIdx.x / NE;
        const int e = blockIdx.x - a*NE;
        if (e >= ent[a]) return;

        float* VT   = (float*)pool;            // [512][36]
        float* simv = (float*)(pool + 73728);  // [32]
        int*   indv = (int*)(pool + 73856);    // [32]
        float* scl  = (float*)(pool + 73984);  // [32]
        float* wsum = (float*)(pool + 74112);  // [4]
        float* wcnt = (float*)(pool + 74128);  // [4]

        if (t < NS) {
            int q = a*NS + t;
            simv[t] = out_ro[OUT_SIM_OFF + (size_t)q*NC + a*NE + e];
            indv[t] = (int)out_ro[(size_t)q*NC + a*NE + e];
        }
        __syncthreads();
        if (t < NS) {
            float v = simv[t];
            float mn = v, mx = v;
            #pragma unroll
            for (int off = 16; off >= 1; off >>= 1) {
                mn = fminf(mn, __shfl_xor(mn, off));
                mx = fmaxf(mx, __shfl_xor(mx, off));
            }
            simv[t] = (v - mn) / (mx - mn + EPSF);
        }
        __syncthreads();

        const int g = t >> 3, j = t & 7;
        const float* src = vis + (size_t)indv[g]*DD;
        float ss = 0.f;
        #pragma unroll
        for (int i = 0; i < 16; i++) {
            int k4 = j + 8*i;
            float4 v = *(const float4*)(src + k4*4);
            ss = fmaf(v.x,v.x, fmaf(v.y,v.y, fmaf(v.z,v.z, fmaf(v.w,v.w, ss))));
            int k = k4*4;
            VT[(k+0)*36 + g] = v.x;
            VT[(k+1)*36 + g] = v.y;
            VT[(k+2)*36 + g] = v.z;
            VT[(k+3)*36 + g] = v.w;
        }
        #pragma unroll
        for (int off = 4; off >= 1; off >>= 1) ss += __shfl_xor(ss, off);
        if (j == 0) scl[g] = simv[g] / (sqrtf(ss) + EPSF);
        __syncthreads();

        const int s = t >> 3, tq = t & 7;
        float g0=0.f, g1=0.f, g2=0.f, g3=0.f;
        for (int k = 0; k < DD; k++) {
            float vs = VT[k*36 + s];
            float4 vt = *(const float4*)&VT[k*36 + tq*4];
            g0 = fmaf(vs, vt.x, g0);
            g1 = fmaf(vs, vt.y, g1);
            g2 = fmaf(vs, vt.z, g2);
            g3 = fmaf(vs, vt.w, g3);
        }
        float lsum = 0.f, lcnt = 0.f;
        float sc_s = scl[s];
        float gv[4] = {g0, g1, g2, g3};
        #pragma unroll
        for (int jj = 0; jj < 4; jj++) {
            int tt = tq*4 + jj;
            if (tt != s) {
                float val = 1.f - sc_s * scl[tt] * gv[jj];
                lsum += val;
                if (val != 0.f) lcnt += 1.f;
            }
        }
        #pragma unroll
        for (int off = 32; off >= 1; off >>= 1) {
            lsum += __shfl_xor(lsum, off);
            lcnt += __shfl_xor(lcnt, off);
        }
        const int wid = t >> 6, lane = t & 63;
        if (lane == 0) { wsum[wid] = lsum; wcnt[wid] = lcnt; }
        __syncthreads();
        if (t == 0) {
            atomicAdd(&ws[0], wsum[0]+wsum[1]+wsum[2]+wsum[3]);
            atomicAdd(&ws[1], wcnt[0]+wcnt[1]+wcnt[2]+wcnt[3]);
        }
    } else {
        // ================= K3 body: per a margin Sf ==============================
        const int a = blockIdx.x - 192;
        float* Ss  = (float*)pool;             // [32][192]
        float* Smn = (float*)(pool + 24576);   // [192]
        float* Smx = (float*)(pool + 25344);   // [192]

        for (int e2 = t; e2 < NS*NC; e2 += 256) {
            int s = e2 / NC, c = e2 - (e2/NC)*NC;
            Ss[s*NC + c] = out_ro[OUT_SIM_OFF + (size_t)(a*NS + s)*NC + c];
        }
        __syncthreads();
        if (t < NC) {
            float mn = INFINITY, mx = -INFINITY;
            #pragma unroll
            for (int s = 0; s < NS; s++) {
                float v = Ss[s*NC + t];
                mn = fminf(mn, v); mx = fmaxf(mx, v);
            }
            Smn[t] = mn; Smx[t] = mx;
        }
        __syncthreads();
        for (int p = t; p < NS*NA; p += 256) {
            int s = p >> 4, b = p & 15;
            int eb = ent[b];
            float dv = (eb == 0) ? 1.f : (float)eb;
            float sum = 0.f;
            #pragma unroll
            for (int e2 = 0; e2 < NE; e2++) {
                int c = b*NE + e2;
                float S = Ss[s*NC + c];
                float r = (S - Smn[c]) / (Smx[c] - Smn[c] + EPSF);
                sum += S * r;
            }
            ws[2 + a*(NS*NA) + s*NA + b] = sum / dv;
        }
    }
}

// ---------------- K4: final combine ----------------------------------------------
__global__ __launch_bounds__(256) void k4_final(
    const float* __restrict__ ws_ro, float* __restrict__ out)
{
    __shared__ float Sf[NA][NS][NA];
    __shared__ float dg[NA][NS];
    __shared__ float wred[4];
    const int t = threadIdx.x;
    for (int e2 = t; e2 < NA*NS*NA; e2 += 256)
        ((float*)Sf)[e2] = ws_ro[2 + e2];
    __syncthreads();
    for (int p = t; p < NA*NS; p += 256) {
        int aa = p >> 5, s = p & 31;
        dg[aa][s] = Sf[aa][s][aa];
    }
    __syncthreads();
    float fsum = 0.f;
    for (int p = t; p < NA*NS; p += 256) {
        int i = p >> 5, s = p & 31;
        float d = dg[i][s];
        float t1 = 0.f, t2 = 0.f;
        #pragma unroll
        for (int x = 0; x < NA; x++) {
            t1 += fmaxf(Sf[x][s][i] - d + DELTAF, 0.f);
            t2 += fmaxf(Sf[i][s][x] - d + DELTAF, 0.f);
        }
        fsum += (t1 + t2) * (1.f/16.f);
    }
    #pragma unroll
    for (int off = 32; off >= 1; off >>= 1) fsum += __shfl_xor(fsum, off);
    const int wid = t >> 6, lane = t & 63;
    if (lane == 0) wred[wid] = fsum;
    __syncthreads();
    if (t == 0) {
        float frame_mean = (wred[0]+wred[1]+wred[2]+wred[3]) / 512.f;
        float vis_loss = ws_ro[0] / ws_ro[1];
        out[2*OUT_SIM_OFF] = (frame_mean + 1.0f * vis_loss) * 10.f;
    }
}

extern "C" void kernel_launch(void* const* d_in, const int* in_sizes, int n_in,
                              void* d_out, int out_size, void* d_ws, size_t ws_size,
                              hipStream_t stream)
{
    (void)in_sizes; (void)n_in; (void)out_size; (void)ws_size;
    const float* vis  = (const float*)d_in[0];
    const float* word = (const float*)d_in[1];
    const int*   ent  = (const int*)d_in[2];
    float* out = (float*)d_out;
    float* ws  = (float*)d_ws;
    const unsigned short* wsB = (const unsigned short*)(ws + WS_B_FOFF);

    k0_conv<<<192, 64, 0, stream>>>(word, ws);
    k1_mfma<<<NQ, 512, 0, stream>>>(vis, word, wsB, ent, out);
    k23_fused<<<208, 256, 0, stream>>>(vis, ent, out, ws);
    k4_final<<<1, 256, 0, stream>>>(ws, out);
}